// Round 11
// baseline (205.403 us; speedup 1.0000x reference)
//
#include <hip/hip_runtime.h>

// Problem constants (match reference)
#define B 32
#define S 32
#define N 128
#define U 64
#define E 2
#define NCLS 5

// R18: kill instructions+bytes at the source. R8-R17 nulls show serving pipe
// (L1/L2/LDS) is irrelevant -- the invariant is ~380 scalar weight-load
// instructions per wave per step and per-CU weight bytes. Two cuts:
// (1) one-time pre-transpose of all 16 UxU weight mats to float4 rows
//     (Wt[u/4][v] = {W[4u..4u+3][v]}): weight load instrs / 4, FMA order
//     per accumulator unchanged (u ascending) -> bit-identical.
// (2) 8 rows/wave x split-K=4 (R16's proven reduce, absmax 0.0): per-CU
//     weight bytes 1MB -> 256KB/step (weights feed 8 rows, not 2).
// Shape: 512 blocks x 256 thr (1 row-group of 8 rows per block, 4 waves =
// k-quarters), 2 blocks/CU, 8 waves/CU. LDS 32KB reduce scratch, 4 syncs.

__device__ __forceinline__ float sigmoid_f(float x) {
    return __fdividef(1.f, 1.f + __expf(-x));
}
__device__ __forceinline__ float tanh_f(float x) {
    float t = __expf(-2.f * fabsf(x));
    float y = __fdividef(1.f - t, 1.f + t);
    return copysignf(y, x);
}
// broadcast lane u's value of v to all lanes (VALU pipe, no LDS)
__device__ __forceinline__ float bcast(float v, int u) {
    return __uint_as_float(__builtin_amdgcn_readlane(__float_as_uint(v), u));
}

// ---------------------------------------------------------------------------
// k_prep: repack 16 UxU matrices into float4-transposed form.
// mat order: Wmsg l0e0,l0e1,l1e0,l1e1 (0-3); Wg l0:0-2,l1:0-2 (4-9); Ug (10-15)
__global__ __launch_bounds__(256) void k_prep(
    const float* __restrict__ Wmsg, const float* __restrict__ Wg,
    const float* __restrict__ Ug, float4* __restrict__ wt) {
    int m = blockIdx.x;
    const float* src;
    if (m < 4)       src = Wmsg + (size_t)m * U * U;
    else if (m < 10) src = Wg + (size_t)(m - 4) * U * U;
    else             src = Ug + (size_t)(m - 10) * U * U;
    for (int i = threadIdx.x; i < (U / 4) * U; i += 256) {
        int u4 = i >> 6, v = i & 63;
        wt[(size_t)m * 1024 + i] =
            make_float4(src[(u4 * 4 + 0) * U + v], src[(u4 * 4 + 1) * U + v],
                        src[(u4 * 4 + 2) * U + v], src[(u4 * 4 + 3) * U + v]);
    }
}

template <int FIRST, int LAST>
__global__ __launch_bounds__(256, 4) void k_step(
    const float* __restrict__ x, const int* __restrict__ lens,
    const float* __restrict__ hin, float* __restrict__ hout,
    const float* __restrict__ A, const float4* __restrict__ wt,
    const float* __restrict__ bmsg, const float* __restrict__ bg,
    const float* __restrict__ fcw, float* __restrict__ partial, int l) {
    __shared__ float sA[4][8][2][64];  // 16 KB: P1 s, P3 z/r
    __shared__ float sB[4][8][64];     //  8 KB: P2 av, P5 c2
    __shared__ float sC[4][8][64];     //  8 KB: P3 c
    int tid = threadIdx.x;
    int k = __builtin_amdgcn_readfirstlane(tid >> 6);  // split-K quarter
    int lane = tid & 63;
    int b = blockIdx.x >> 4;
    int j = blockIdx.x & 15;             // row-group (8 rows) within batch
    int n0 = __builtin_amdgcn_readfirstlane(j * 8);
    int m0 = __builtin_amdgcn_readfirstlane(k * 32);   // m-quarter

    const float* __restrict__ hsrc;
    if (FIRST) {
        int idx = lens[b] - 1;
        idx = idx < 0 ? 0 : (idx > S - 1 ? S - 1 : idx);
        hsrc = x + (size_t)(b * S + idx) * N * U;
    } else {
        hsrc = hin + (size_t)b * N * U;
    }

    float hv[8];
#pragma unroll
    for (int r = 0; r < 8; ++r) hv[r] = hsrc[(n0 + r) * U + lane];

    // ---- P1: aggregate partials over this wave's m-quarter (32 m's),
    //          one edge at a time (register pressure). Per-acc m ascending.
    float s2[8][2];
#pragma unroll
    for (int e = 0; e < E; ++e) {
        float acc[8];
#pragma unroll
        for (int r = 0; r < 8; ++r) acc[r] = 0.f;
        const float4* Ap[8];
#pragma unroll
        for (int r = 0; r < 8; ++r)
            Ap[r] = (const float4*)(A + (((size_t)b * E + e) * N + n0 + r) * N + m0);
#pragma unroll 2
        for (int m4 = 0; m4 < 8; ++m4) {
            float q0 = hsrc[(m0 + m4 * 4 + 0) * U + lane];
            float q1 = hsrc[(m0 + m4 * 4 + 1) * U + lane];
            float q2 = hsrc[(m0 + m4 * 4 + 2) * U + lane];
            float q3 = hsrc[(m0 + m4 * 4 + 3) * U + lane];
#pragma unroll
            for (int r = 0; r < 8; ++r) {
                float4 a = Ap[r][m4];
                acc[r] = fmaf(a.x, q0, acc[r]);
                acc[r] = fmaf(a.y, q1, acc[r]);
                acc[r] = fmaf(a.z, q2, acc[r]);
                acc[r] = fmaf(a.w, q3, acc[r]);
            }
        }
#pragma unroll
        for (int r = 0; r < 8; ++r) s2[r][e] = acc[r];
    }
#pragma unroll
    for (int r = 0; r < 8; ++r) {
        sA[k][r][0][lane] = s2[r][0];
        sA[k][r][1][lane] = s2[r][1];
    }
    __syncthreads();  // sync1
#pragma unroll
    for (int r = 0; r < 8; ++r) {
        s2[r][0] = (sA[0][r][0][lane] + sA[1][r][0][lane]) + (sA[2][r][0][lane] + sA[3][r][0][lane]);
        s2[r][1] = (sA[0][r][1][lane] + sA[1][r][1][lane]) + (sA[2][r][1][lane] + sA[3][r][1][lane]);
    }

    // ---- P2: msg partials over this wave's u-quarter (16 u's), float4 wts
    float av[8];
    {
        float bm = (k == 0) ? bmsg[l * U + lane] : 0.f;
#pragma unroll
        for (int r = 0; r < 8; ++r) av[r] = bm;
        const float4* W0t = wt + (size_t)(l * E + 0) * 1024 + lane;
        const float4* W1t = W0t + 1024;
#pragma unroll
        for (int u4 = 0; u4 < 4; ++u4) {
            float4 w4 = W0t[(k * 4 + u4) * 64];
#pragma unroll
            for (int i = 0; i < 4; ++i) {
                int u = k * 16 + u4 * 4 + i;
                float wv = ((const float*)&w4)[i];
#pragma unroll
                for (int r = 0; r < 8; ++r) av[r] = fmaf(bcast(s2[r][0], u), wv, av[r]);
            }
        }
#pragma unroll
        for (int u4 = 0; u4 < 4; ++u4) {
            float4 w4 = W1t[(k * 4 + u4) * 64];
#pragma unroll
            for (int i = 0; i < 4; ++i) {
                int u = k * 16 + u4 * 4 + i;
                float wv = ((const float*)&w4)[i];
#pragma unroll
                for (int r = 0; r < 8; ++r) av[r] = fmaf(bcast(s2[r][1], u), wv, av[r]);
            }
        }
    }
#pragma unroll
    for (int r = 0; r < 8; ++r) sB[k][r][lane] = av[r];
    __syncthreads();  // sync2
#pragma unroll
    for (int r = 0; r < 8; ++r)
        av[r] = (sB[0][r][lane] + sB[1][r][lane]) + (sB[2][r][lane] + sB[3][r][lane]);

    // ---- P3: gate matmul partials over this wave's u-quarter, float4 wts
    float accz[8], accr[8], accc[8];
    {
        float bz = (k == 0) ? bg[(l * 3 + 0) * U + lane] : 0.f;
        float br = (k == 0) ? bg[(l * 3 + 1) * U + lane] : 0.f;
        float bcc = (k == 0) ? bg[(l * 3 + 2) * U + lane] : 0.f;
#pragma unroll
        for (int r = 0; r < 8; ++r) { accz[r] = bz; accr[r] = br; accc[r] = bcc; }
        const float4* Wg0t = wt + (size_t)(4 + l * 3 + 0) * 1024 + lane;
        const float4* Wg1t = Wg0t + 1024;
        const float4* Wg2t = Wg1t + 1024;
        const float4* Ug0t = wt + (size_t)(10 + l * 3 + 0) * 1024 + lane;
        const float4* Ug1t = Ug0t + 1024;
#pragma unroll
        for (int u4 = 0; u4 < 4; ++u4) {
            float4 w0 = Wg0t[(k * 4 + u4) * 64];
            float4 w1 = Wg1t[(k * 4 + u4) * 64];
            float4 w2 = Wg2t[(k * 4 + u4) * 64];
            float4 g0 = Ug0t[(k * 4 + u4) * 64];
            float4 g1 = Ug1t[(k * 4 + u4) * 64];
#pragma unroll
            for (int i = 0; i < 4; ++i) {
                int u = k * 16 + u4 * 4 + i;
                float w0v = ((const float*)&w0)[i], w1v = ((const float*)&w1)[i];
                float w2v = ((const float*)&w2)[i];
                float g0v = ((const float*)&g0)[i], g1v = ((const float*)&g1)[i];
#pragma unroll
                for (int r = 0; r < 8; ++r) {
                    float a = bcast(av[r], u);
                    float h = bcast(hv[r], u);
                    accz[r] = fmaf(a, w0v, accz[r]); accz[r] = fmaf(h, g0v, accz[r]);
                    accr[r] = fmaf(a, w1v, accr[r]); accr[r] = fmaf(h, g1v, accr[r]);
                    accc[r] = fmaf(a, w2v, accc[r]);
                }
            }
        }
    }
#pragma unroll
    for (int r = 0; r < 8; ++r) {
        sA[k][r][0][lane] = accz[r];
        sA[k][r][1][lane] = accr[r];
        sC[k][r][lane] = accc[r];
    }
    __syncthreads();  // sync3
#pragma unroll
    for (int r = 0; r < 8; ++r) {
        accz[r] = (sA[0][r][0][lane] + sA[1][r][0][lane]) + (sA[2][r][0][lane] + sA[3][r][0][lane]);
        accr[r] = (sA[0][r][1][lane] + sA[1][r][1][lane]) + (sA[2][r][1][lane] + sA[3][r][1][lane]);
        accc[r] = (sC[0][r][lane] + sC[1][r][lane]) + (sC[2][r][lane] + sC[3][r][lane]);
    }

    // ---- P5: rh matmul partials over this wave's u-quarter
    float rh[8];
#pragma unroll
    for (int r = 0; r < 8; ++r) rh[r] = sigmoid_f(accr[r]) * hv[r];
    {
        const float4* Ug2t = wt + (size_t)(10 + l * 3 + 2) * 1024 + lane;
        float c2[8];
#pragma unroll
        for (int r = 0; r < 8; ++r) c2[r] = 0.f;
#pragma unroll
        for (int u4 = 0; u4 < 4; ++u4) {
            float4 g2 = Ug2t[(k * 4 + u4) * 64];
#pragma unroll
            for (int i = 0; i < 4; ++i) {
                int u = k * 16 + u4 * 4 + i;
                float g2v = ((const float*)&g2)[i];
#pragma unroll
                for (int r = 0; r < 8; ++r) c2[r] = fmaf(bcast(rh[r], u), g2v, c2[r]);
            }
        }
#pragma unroll
        for (int r = 0; r < 8; ++r) sB[k][r][lane] = c2[r];  // av reads done pre-sync3
    }
    __syncthreads();  // sync4
#pragma unroll
    for (int r = 0; r < 8; ++r)
        accc[r] += (sB[0][r][lane] + sB[1][r][lane]) + (sB[2][r][lane] + sB[3][r][lane]);

    float hn[8];
#pragma unroll
    for (int r = 0; r < 8; ++r) {
        float zg = sigmoid_f(accz[r]);
        hn[r] = (1.f - zg) * hv[r] + zg * tanh_f(accc[r]);
    }

    if (!LAST) {
        if (k == 0) {
#pragma unroll
            for (int r = 0; r < 8; ++r)
                hout[((size_t)b * N + n0 + r) * U + lane] = hn[r];
        }
    } else {
        // classification partial over this block's 8 rows (k==0 wave only)
        if (k == 0) {
            float mc[NCLS];
#pragma unroll
            for (int c = 0; c < NCLS; ++c) mc[c] = -3.4e38f;
#pragma unroll
            for (int r = 0; r < 8; ++r) {
                float rv = hn[r] > 0.f ? hn[r] : 0.f;
                float lg[NCLS];
#pragma unroll
                for (int c = 0; c < NCLS; ++c) lg[c] = rv * fcw[lane * NCLS + c];
#pragma unroll
                for (int off = 32; off; off >>= 1)
#pragma unroll
                    for (int c = 0; c < NCLS; ++c) lg[c] += __shfl_xor(lg[c], off, 64);
#pragma unroll
                for (int c = 0; c < NCLS; ++c) mc[c] = fmaxf(mc[c], lg[c]);
            }
            if (lane == 0) {
#pragma unroll
                for (int c = 0; c < NCLS; ++c)
                    partial[(size_t)(b * 16 + j) * NCLS + c] = mc[c];
            }
        }
    }
}

// ---------------------------------------------------------------------------
// k_final: out[b][c] = max over 16 row-group partials + fc_b
__global__ void k_final(const float* __restrict__ partial, const float* __restrict__ fcb,
                        float* __restrict__ out) {
    int b = blockIdx.x, c = threadIdx.x;
    if (c < NCLS) {
        float m = -3.4e38f;
        for (int jj = 0; jj < 16; ++jj)
            m = fmaxf(m, partial[(size_t)(b * 16 + jj) * NCLS + c]);
        out[b * NCLS + c] = m + fcb[c];
    }
}

// ---------------------------------------------------------------------------
extern "C" void kernel_launch(void* const* d_in, const int* in_sizes, int n_in,
                              void* d_out, int out_size, void* d_ws, size_t ws_size,
                              hipStream_t stream) {
    const float* x    = (const float*)d_in[0];
    const int*   lens = (const int*)d_in[1];
    const float* A    = (const float*)d_in[2];
    const float* Wmsg = (const float*)d_in[3];
    const float* bmsg = (const float*)d_in[4];
    const float* Wg   = (const float*)d_in[5];
    const float* Ug   = (const float*)d_in[6];
    const float* bg   = (const float*)d_in[7];
    const float* fcw  = (const float*)d_in[8];
    const float* fcb  = (const float*)d_in[9];
    float* out = (float*)d_out;

    float* hA      = (float*)d_ws;                   // [B][N][U]
    float* hB      = hA + (size_t)B * N * U;         // [B][N][U]
    float* partial = hB + (size_t)B * N * U;         // [B][16][NCLS]
    float4* wt     = (float4*)(partial + (size_t)B * 16 * NCLS);  // 16 mats

    k_prep<<<16, 256, 0, stream>>>(Wmsg, Wg, Ug, wt);
    // steps 0-2: layer 0; steps 3-5: layer 1
    k_step<1, 0><<<B * 16, 256, 0, stream>>>(x, lens, nullptr, hA, A, wt, bmsg, bg, fcw, partial, 0);
    k_step<0, 0><<<B * 16, 256, 0, stream>>>(x, lens, hA, hB, A, wt, bmsg, bg, fcw, partial, 0);
    k_step<0, 0><<<B * 16, 256, 0, stream>>>(x, lens, hB, hA, A, wt, bmsg, bg, fcw, partial, 0);
    k_step<0, 0><<<B * 16, 256, 0, stream>>>(x, lens, hA, hB, A, wt, bmsg, bg, fcw, partial, 1);
    k_step<0, 0><<<B * 16, 256, 0, stream>>>(x, lens, hB, hA, A, wt, bmsg, bg, fcw, partial, 1);
    k_step<0, 1><<<B * 16, 256, 0, stream>>>(x, lens, hA, hB, A, wt, bmsg, bg, fcw, partial, 1);
    k_final<<<B, 64, 0, stream>>>(partial, fcb, out);
}